// Round 1
// baseline (577.993 us; speedup 1.0000x reference)
//
#include <hip/hip_runtime.h>
#include <hip/hip_bf16.h>
#include <math.h>

#define EE 300
#define QQ 64
#define DD 4096
#define NEG 0.01f

// -------- gather rows of emb --------
__global__ void gather_rows(const float* __restrict__ emb, const int* __restrict__ idx,
                            float* __restrict__ out, int nrows) {
  int row = blockIdx.x;
  if (row >= nrows) return;
  const float* src = emb + (size_t)idx[row] * EE;
  float* dst = out + (size_t)row * EE;
  for (int i = threadIdx.x; i < EE; i += blockDim.x) dst[i] = src[i];
}

// -------- per-row L2 norms (one wave per row) --------
__global__ void row_norms(const float* __restrict__ x, float* __restrict__ nrm, int nrows) {
  int wid = (int)((blockIdx.x * blockDim.x + threadIdx.x) >> 6);
  int lane = threadIdx.x & 63;
  if (wid >= nrows) return;
  const float* r = x + (size_t)wid * EE;
  float s = 0.f;
  for (int i = lane; i < EE; i += 64) { float v = r[i]; s += v * v; }
  #pragma unroll
  for (int o = 32; o; o >>= 1) s += __shfl_xor(s, o);
  if (lane == 0) nrm[wid] = sqrtf(s);
}

// -------- conv1d(E,E,3, SAME) + bias + leaky + residual --------
// out[l][o] = leaky(b[o] + sum_{i,k} w[o][i][k]*x[l+k-1][i]) + x[l][o]
__global__ __launch_bounds__(320) void conv_residual(
    const float* __restrict__ x, const float* __restrict__ w,
    const float* __restrict__ b, float* __restrict__ out, int L) {
  __shared__ float tile[18][EE];  // rows l0-1 .. l0+16
  int l0 = blockIdx.x * 16;
  for (int t = threadIdx.x; t < 18 * EE; t += blockDim.x) {
    int r = t / EE, i = t - r * EE;
    int l = l0 + r - 1;
    tile[r][i] = (l >= 0 && l < L) ? x[(size_t)l * EE + i] : 0.f;
  }
  __syncthreads();
  int o = threadIdx.x;
  if (o >= EE) return;
  float acc[16];
  #pragma unroll
  for (int r = 0; r < 16; ++r) acc[r] = 0.f;
  const float* wo = w + (size_t)o * (EE * 3);
  for (int i = 0; i < EE; ++i) {
    float w0 = wo[3 * i], w1 = wo[3 * i + 1], w2 = wo[3 * i + 2];
    // LDS reads are wave-uniform (same address on all lanes -> broadcast, free)
    #pragma unroll
    for (int r = 0; r < 16; ++r)
      acc[r] += w0 * tile[r][i] + w1 * tile[r + 1][i] + w2 * tile[r + 2][i];
  }
  float bo = b[o];
  int nrows = min(16, L - l0);
  for (int r = 0; r < nrows; ++r) {
    float y = acc[r] + bo;
    y = (y >= 0.f) ? y : NEG * y;
    out[(size_t)(l0 + r) * EE + o] = y + tile[r + 1][o];
  }
}

// -------- cosine-sim GEMM: C[q][l] = dot(A[q],B[l]) / (na[q]*nb[l]) --------
__global__ __launch_bounds__(256) void sim_gemm(
    const float* __restrict__ A, const float* __restrict__ B,
    const float* __restrict__ na, const float* __restrict__ nb,
    float* __restrict__ C, int Lb) {
  __shared__ float As[QQ][31];
  __shared__ float Bs[64][31];
  int l0 = blockIdx.x * 64;
  int tid = threadIdx.x;
  int tq = (tid >> 4) << 2;   // 4 q rows per thread
  int tl = (tid & 15) << 2;   // 4 l cols per thread
  float acc[4][4];
  #pragma unroll
  for (int qi = 0; qi < 4; ++qi)
    #pragma unroll
    for (int li = 0; li < 4; ++li) acc[qi][li] = 0.f;
  for (int k0 = 0; k0 < EE; k0 += 30) {
    for (int t = tid; t < 64 * 30; t += 256) {
      int r = t / 30, c = t - r * 30;
      As[r][c] = A[r * EE + k0 + c];
      Bs[r][c] = B[(size_t)(l0 + r) * EE + k0 + c];
    }
    __syncthreads();
    #pragma unroll
    for (int kk = 0; kk < 30; ++kk) {
      float a[4], bb[4];
      #pragma unroll
      for (int j = 0; j < 4; ++j) a[j] = As[tq + j][kk];
      #pragma unroll
      for (int j = 0; j < 4; ++j) bb[j] = Bs[tl + j][kk];
      #pragma unroll
      for (int qi = 0; qi < 4; ++qi)
        #pragma unroll
        for (int li = 0; li < 4; ++li) acc[qi][li] += a[qi] * bb[li];
    }
    __syncthreads();
  }
  #pragma unroll
  for (int qi = 0; qi < 4; ++qi) {
    float ia = 1.f / na[tq + qi];
    #pragma unroll
    for (int li = 0; li < 4; ++li)
      C[(size_t)(tq + qi) * Lb + (l0 + tl + li)] = acc[qi][li] * ia / nb[l0 + tl + li];
  }
}

// -------- top-5 pooling --------
__device__ inline void top5_insert(float* t, float v) {
  if (v > t[4]) {
    t[4] = v;
    #pragma unroll
    for (int j = 4; j > 0; --j) {
      if (t[j] > t[j - 1]) { float tmp = t[j]; t[j] = t[j - 1]; t[j - 1] = tmp; }
    }
  }
}

// grid: (64 q, 6 src). src: 0=oh_d1 1=ins_d1 2=sen_d1 3=oh_d2 4=ins_d2 5=sen_d2
__global__ __launch_bounds__(256) void kmax_pool(
    const float* __restrict__ d1sim, const float* __restrict__ d2sim,
    const float* __restrict__ sims, float* __restrict__ pool) {
  int q = blockIdx.x, src = blockIdx.y;
  int tid = threadIdx.x;
  const size_t QD = (size_t)QQ * DD;
  float t5[5];
  #pragma unroll
  for (int j = 0; j < 5; ++j) t5[j] = -1e30f;
  for (int l = tid; l < DD; l += 256) {
    float v;
    switch (src) {
      case 0: v = d1sim[(size_t)l * QQ + q]; break;          // doc1_sim.T
      case 1: v = sims[0 * QD + (size_t)q * DD + l]; break;  // ins_d1
      case 2: v = sims[2 * QD + (size_t)q * DD + l]; break;  // sen_d1
      case 3: v = d2sim[(size_t)l * QQ + q]; break;          // doc2_sim.T
      case 4: v = sims[1 * QD + (size_t)q * DD + l]; break;  // ins_d2
      default: v = sims[3 * QD + (size_t)q * DD + l]; break; // sen_d2
    }
    top5_insert(t5, v);
  }
  __shared__ float ls[256][5];
  #pragma unroll
  for (int j = 0; j < 5; ++j) ls[tid][j] = t5[j];
  __syncthreads();
  for (int step = 128; step >= 1; step >>= 1) {
    if (tid < step) {
      float a[5], c[5], m[5];
      #pragma unroll
      for (int j = 0; j < 5; ++j) { a[j] = ls[tid][j]; c[j] = ls[tid + step][j]; }
      int ia = 0, ib = 0;
      #pragma unroll
      for (int j = 0; j < 5; ++j) m[j] = (a[ia] >= c[ib]) ? a[ia++] : c[ib++];
      #pragma unroll
      for (int j = 0; j < 5; ++j) ls[tid][j] = m[j];
    }
    __syncthreads();
  }
  if (tid == 0) {
    float mx = ls[0][0];
    float sm = 0.f;
    #pragma unroll
    for (int j = 0; j < 5; ++j) sm += ls[0][j];
    pool[((size_t)src * QQ + q) * 2 + 0] = mx;
    pool[((size_t)src * QQ + q) * 2 + 1] = sm * 0.2f;
  }
}

// -------- final: qw + softmax + MLP + epilogue (one wave) --------
__global__ void final_kernel(
    const float* __restrict__ qconv, const float* __restrict__ idf,
    const int* __restrict__ question, const float* __restrict__ qw_w,
    const float* __restrict__ qw_b, const float* __restrict__ pool,
    const float* __restrict__ lin1_w, const float* __restrict__ lin2_w,
    const float* __restrict__ out_w, const float* __restrict__ gaf,
    const float* __restrict__ baf, float* __restrict__ out5) {
  int q = threadIdx.x;  // 64 threads = one wave
  const float* row = qconv + (size_t)q * EE;
  float s = qw_b[0];
  for (int i = 0; i < EE; ++i) s += row[i] * qw_w[i];
  s += idf[question[q]] * qw_w[EE];
  float m = s;
  #pragma unroll
  for (int o = 32; o; o >>= 1) m = fmaxf(m, __shfl_xor(m, o));
  float e = expf(s - m);
  float se = e;
  #pragma unroll
  for (int o = 32; o; o >>= 1) se += __shfl_xor(se, o);
  float qwgt = e / se;

  float emit[2];
  for (int doc = 0; doc < 2; ++doc) {
    float temp[6];
    #pragma unroll
    for (int j = 0; j < 3; ++j) {
      temp[2 * j]     = pool[(((size_t)doc * 3 + j) * QQ + q) * 2 + 0];
      temp[2 * j + 1] = pool[(((size_t)doc * 3 + j) * QQ + q) * 2 + 1];
    }
    float lo = 0.f;
    #pragma unroll
    for (int r = 0; r < 8; ++r) {
      float h = 0.f;
      #pragma unroll
      for (int c = 0; c < 6; ++c) h += lin1_w[r * 6 + c] * temp[c];
      h = (h >= 0.f) ? h : NEG * h;
      lo += lin2_w[r] * h;
    }
    lo *= qwgt;
    #pragma unroll
    for (int o = 32; o; o >>= 1) lo += __shfl_xor(lo, o);
    emit[doc] = lo / (float)QQ;
  }
  if (q == 0) {
    float good = out_w[0] * gaf[0] + out_w[1] * gaf[1] + out_w[2] * gaf[2] +
                 out_w[3] * gaf[3] + out_w[4] * emit[0];
    float bad  = out_w[0] * baf[0] + out_w[1] * baf[1] + out_w[2] * baf[2] +
                 out_w[3] * baf[3] + out_w[4] * emit[1];
    float l1 = fmaxf(0.f, -(good - bad) + 1.f);
    out5[0] = l1; out5[1] = good; out5[2] = bad; out5[3] = l1; out5[4] = l1;
  }
}

extern "C" void kernel_launch(void* const* d_in, const int* in_sizes, int n_in,
                              void* d_out, int out_size, void* d_ws, size_t ws_size,
                              hipStream_t stream) {
  (void)in_sizes; (void)n_in; (void)out_size; (void)ws_size;
  const int* question   = (const int*)d_in[0];
  const int* doc1       = (const int*)d_in[1];
  const int* doc2       = (const int*)d_in[2];
  const float* doc1_sim = (const float*)d_in[3];
  const float* doc2_sim = (const float*)d_in[4];
  const float* gaf      = (const float*)d_in[5];
  const float* baf      = (const float*)d_in[6];
  const float* emb      = (const float*)d_in[7];
  const float* idf      = (const float*)d_in[8];
  const float* conv_w   = (const float*)d_in[9];
  const float* conv_b   = (const float*)d_in[10];
  const float* qw_w     = (const float*)d_in[11];
  const float* qw_b     = (const float*)d_in[12];
  const float* lin1_w   = (const float*)d_in[13];
  const float* lin2_w   = (const float*)d_in[14];
  const float* out_w    = (const float*)d_in[15];
  float* out = (float*)d_out;

  float* p = (float*)d_ws;
  float* q_emb   = p; p += QQ * EE;
  float* d1_emb  = p; p += (size_t)DD * EE;
  float* d2_emb  = p; p += (size_t)DD * EE;
  float* q_conv  = p; p += QQ * EE;
  float* d1_conv = p; p += (size_t)DD * EE;
  float* d2_conv = p; p += (size_t)DD * EE;
  float* sims    = p; p += (size_t)4 * QQ * DD;  // ins1, ins2, sen1, sen2
  float* nq   = p; p += QQ;
  float* nd1  = p; p += DD;
  float* nd2  = p; p += DD;
  float* nqc  = p; p += QQ;
  float* nd1c = p; p += DD;
  float* nd2c = p; p += DD;
  float* pool = p; p += 6 * QQ * 2;

  const size_t QD = (size_t)QQ * DD;

  gather_rows<<<QQ, 256, 0, stream>>>(emb, question, q_emb, QQ);
  gather_rows<<<DD, 256, 0, stream>>>(emb, doc1, d1_emb, DD);
  gather_rows<<<DD, 256, 0, stream>>>(emb, doc2, d2_emb, DD);

  row_norms<<<QQ / 4, 256, 0, stream>>>(q_emb, nq, QQ);
  row_norms<<<DD / 4, 256, 0, stream>>>(d1_emb, nd1, DD);
  row_norms<<<DD / 4, 256, 0, stream>>>(d2_emb, nd2, DD);

  conv_residual<<<QQ / 16, 320, 0, stream>>>(q_emb, conv_w, conv_b, q_conv, QQ);
  conv_residual<<<DD / 16, 320, 0, stream>>>(d1_emb, conv_w, conv_b, d1_conv, DD);
  conv_residual<<<DD / 16, 320, 0, stream>>>(d2_emb, conv_w, conv_b, d2_conv, DD);

  row_norms<<<QQ / 4, 256, 0, stream>>>(q_conv, nqc, QQ);
  row_norms<<<DD / 4, 256, 0, stream>>>(d1_conv, nd1c, DD);
  row_norms<<<DD / 4, 256, 0, stream>>>(d2_conv, nd2c, DD);

  sim_gemm<<<DD / 64, 256, 0, stream>>>(q_emb, d1_emb, nq, nd1, sims + 0 * QD, DD);
  sim_gemm<<<DD / 64, 256, 0, stream>>>(q_emb, d2_emb, nq, nd2, sims + 1 * QD, DD);
  sim_gemm<<<DD / 64, 256, 0, stream>>>(q_conv, d1_conv, nqc, nd1c, sims + 2 * QD, DD);
  sim_gemm<<<DD / 64, 256, 0, stream>>>(q_conv, d2_conv, nqc, nd2c, sims + 3 * QD, DD);

  kmax_pool<<<dim3(QQ, 6), 256, 0, stream>>>(doc1_sim, doc2_sim, sims, pool);

  final_kernel<<<1, 64, 0, stream>>>(q_conv, idf, question, qw_w, qw_b, pool,
                                     lin1_w, lin2_w, out_w, gaf, baf, out);
}

// Round 2
// 162.237 us; speedup vs baseline: 3.5626x; 3.5626x over previous
//
#include <hip/hip_runtime.h>
#include <math.h>

#define EE 300
#define EP 304   // fp32 row stride / padded N (19 tiles of 16)
#define KP 320   // padded K stride for bf16 rows (10 k-steps of 32)
#define QQ 64
#define DD 4096
#define NEG 0.01f

typedef __attribute__((ext_vector_type(8))) short short8;
typedef __attribute__((ext_vector_type(4))) float f32x4;

__device__ inline unsigned short f2bf(float f) {
  unsigned int u = __builtin_bit_cast(unsigned int, f);
  u += 0x7fff + ((u >> 16) & 1);   // RNE
  return (unsigned short)(u >> 16);
}

// -------- gather emb rows -> fp32 copy + guarded bf16 copy + row norms --------
// bf16 buffer has 1 zero guard row before and after (conv taps read row-1/row+1).
// Also zeroes the K-pad cols of the conv-output bf16 buffer.
__global__ __launch_bounds__(64) void gather_convert(
    const float* __restrict__ emb, const int* __restrict__ question,
    const int* __restrict__ doc1, const int* __restrict__ doc2,
    float* __restrict__ xq32, float* __restrict__ xd1, float* __restrict__ xd2,
    unsigned short* __restrict__ qbe, unsigned short* __restrict__ d1be,
    unsigned short* __restrict__ d2be,
    unsigned short* __restrict__ qbc, unsigned short* __restrict__ d1bc,
    unsigned short* __restrict__ d2bc,
    float* __restrict__ nq, float* __restrict__ nd1, float* __restrict__ nd2) {
  int t = blockIdx.y;
  const int* idx = t == 0 ? question : (t == 1 ? doc1 : doc2);
  int L = t == 0 ? QQ : DD;
  float* x32 = t == 0 ? xq32 : (t == 1 ? xd1 : xd2);
  unsigned short* be = t == 0 ? qbe : (t == 1 ? d1be : d2be);
  unsigned short* bc = t == 0 ? qbc : (t == 1 ? d1bc : d2bc);
  float* nrm = t == 0 ? nq : (t == 1 ? nd1 : nd2);
  int row = blockIdx.x;
  if (row >= L + 2) return;
  int lane = threadIdx.x;
  if (row == 0 || row == L + 1) {            // zero guard rows
    for (int i = lane; i < KP; i += 64) be[(size_t)row * KP + i] = 0;
    return;
  }
  int r = row - 1;
  const float* src = emb + (size_t)idx[r] * EE;
  float ss = 0.f;
  for (int i = lane; i < EE; i += 64) {
    float v = src[i];
    x32[(size_t)r * EP + i] = v;
    be[(size_t)row * KP + i] = f2bf(v);
    ss += v * v;
  }
  for (int i = EE + lane; i < KP; i += 64) { // zero K-pads
    be[(size_t)row * KP + i] = 0;
    bc[(size_t)r * KP + i] = 0;
  }
  #pragma unroll
  for (int o = 32; o; o >>= 1) ss += __shfl_xor(ss, o);
  if (lane == 0) nrm[r] = sqrtf(ss);
}

// -------- transpose conv weights: wt[tap][o][k] = w[o][k][tap], bf16, padded --------
__global__ __launch_bounds__(64) void wtrans(const float* __restrict__ w,
                                             unsigned short* __restrict__ wt) {
  int o = blockIdx.x;    // 0..303
  int tap = blockIdx.y;  // 0..2
  for (int i = threadIdx.x; i < KP; i += 64) {
    float v = (o < EE && i < EE) ? w[((size_t)o * EE + i) * 3 + tap] : 0.f;
    wt[((size_t)tap * EP + o) * KP + i] = f2bf(v);
  }
}

// -------- conv1d(E,E,3,SAME)+bias+leaky+residual as 3 shifted bf16 MFMA GEMMs --------
// One wave per 16-row M-tile; computes all 304 output channels (19 N-tiles).
// A-frag: 16B contiguous from guarded bf16 rows. B-frag: 16B contiguous from wt.
// Epilogue fuses bias, leaky, fp32 residual, bf16 store and row norms.
__global__ __launch_bounds__(64) void conv_mfma(
    const unsigned short* __restrict__ wt, const float* __restrict__ bias,
    const unsigned short* __restrict__ qbe, const unsigned short* __restrict__ d1be,
    const unsigned short* __restrict__ d2be,
    const float* __restrict__ xq32, const float* __restrict__ xd1,
    const float* __restrict__ xd2,
    unsigned short* __restrict__ qbc, unsigned short* __restrict__ d1bc,
    unsigned short* __restrict__ d2bc,
    float* __restrict__ cq32, float* __restrict__ nqc,
    float* __restrict__ nd1c, float* __restrict__ nd2c) {
  int t = blockIdx.y;
  int L = t == 0 ? QQ : DD;
  int m0 = blockIdx.x * 16;
  if (m0 >= L) return;
  const unsigned short* be = t == 0 ? qbe : (t == 1 ? d1be : d2be);
  const float* x32 = t == 0 ? xq32 : (t == 1 ? xd1 : xd2);
  unsigned short* bc = t == 0 ? qbc : (t == 1 ? d1bc : d2bc);
  float* nrm = t == 0 ? nqc : (t == 1 ? nd1c : nd2c);
  float* q32out = t == 0 ? cq32 : nullptr;

  int lane = threadIdx.x;
  int mrow = lane & 15, g = lane >> 4;
  f32x4 acc[19];
  #pragma unroll
  for (int n = 0; n < 19; ++n) acc[n] = (f32x4){0.f, 0.f, 0.f, 0.f};

  for (int tap = 0; tap < 3; ++tap) {
    const unsigned short* arow = be + (size_t)(m0 + mrow + tap) * KP + g * 8;
    const unsigned short* brow = wt + ((size_t)tap * EP + mrow) * KP + g * 8;
    for (int ks = 0; ks < 10; ++ks) {
      short8 a = *reinterpret_cast<const short8*>(arow + ks * 32);
      #pragma unroll
      for (int n = 0; n < 19; ++n) {
        short8 b = *reinterpret_cast<const short8*>(brow + (size_t)n * 16 * KP + ks * 32);
        acc[n] = __builtin_amdgcn_mfma_f32_16x16x32_bf16(a, b, acc[n], 0, 0, 0);
      }
    }
  }
  // epilogue: C lane layout col = lane&15 (within tile), row = g*4 + r
  float ss[4] = {0.f, 0.f, 0.f, 0.f};
  #pragma unroll
  for (int n = 0; n < 19; ++n) {
    int col = n * 16 + mrow;
    if (col < EE) {
      float bcol = bias[col];
      #pragma unroll
      for (int r = 0; r < 4; ++r) {
        int row = m0 + g * 4 + r;
        float y = acc[n][r] + bcol;
        y = (y >= 0.f) ? y : NEG * y;
        y += x32[(size_t)row * EP + col];
        bc[(size_t)row * KP + col] = f2bf(y);
        if (q32out) q32out[(size_t)row * EP + col] = y;
        ss[r] += y * y;
      }
    }
  }
  #pragma unroll
  for (int r = 0; r < 4; ++r) {
    float s = ss[r];
    s += __shfl_xor(s, 1); s += __shfl_xor(s, 2);
    s += __shfl_xor(s, 4); s += __shfl_xor(s, 8);
    if (mrow == 0) nrm[m0 + g * 4 + r] = sqrtf(s);
  }
}

// -------- cosine sims as bf16 MFMA GEMM, epilogue divides by norms --------
// grid (DD/128, 4 sims); 4 waves/block: wave w = q-tile, 8 N-tiles of l each.
__global__ __launch_bounds__(256) void sim_mfma(
    const unsigned short* __restrict__ qbe, const unsigned short* __restrict__ d1be,
    const unsigned short* __restrict__ d2be,
    const unsigned short* __restrict__ qbc, const unsigned short* __restrict__ d1bc,
    const unsigned short* __restrict__ d2bc,
    const float* __restrict__ nq, const float* __restrict__ nd1,
    const float* __restrict__ nd2, const float* __restrict__ nqc,
    const float* __restrict__ nd1c, const float* __restrict__ nd2c,
    float* __restrict__ sims) {
  int s = blockIdx.y;
  const unsigned short* A = (s < 2) ? qbe + KP : qbc;      // skip guard row
  const unsigned short* B = s == 0 ? d1be + KP : s == 1 ? d2be + KP
                          : s == 2 ? d1bc : d2bc;
  const float* na = (s < 2) ? nq : nqc;
  const float* nb = s == 0 ? nd1 : s == 1 ? nd2 : s == 2 ? nd1c : nd2c;
  float* out = sims + (size_t)s * QQ * DD;
  int l0 = blockIdx.x * 128;
  int w = threadIdx.x >> 6;
  int lane = threadIdx.x & 63;
  int mrow = lane & 15, g = lane >> 4;
  f32x4 acc[8];
  #pragma unroll
  for (int n = 0; n < 8; ++n) acc[n] = (f32x4){0.f, 0.f, 0.f, 0.f};
  const unsigned short* arow = A + (size_t)(w * 16 + mrow) * KP + g * 8;
  const unsigned short* brow = B + (size_t)(l0 + mrow) * KP + g * 8;
  for (int ks = 0; ks < 10; ++ks) {
    short8 a = *reinterpret_cast<const short8*>(arow + ks * 32);
    #pragma unroll
    for (int n = 0; n < 8; ++n) {
      short8 b = *reinterpret_cast<const short8*>(brow + (size_t)n * 16 * KP + ks * 32);
      acc[n] = __builtin_amdgcn_mfma_f32_16x16x32_bf16(a, b, acc[n], 0, 0, 0);
    }
  }
  #pragma unroll
  for (int n = 0; n < 8; ++n) {
    int l = l0 + n * 16 + mrow;
    float inb = 1.f / nb[l];
    #pragma unroll
    for (int r = 0; r < 4; ++r) {
      int q = w * 16 + g * 4 + r;
      out[(size_t)q * DD + l] = acc[n][r] / na[q] * inb;
    }
  }
}

// -------- top-5 pooling --------
__device__ inline void top5_insert(float* t, float v) {
  if (v > t[4]) {
    t[4] = v;
    #pragma unroll
    for (int j = 4; j > 0; --j) {
      if (t[j] > t[j - 1]) { float tmp = t[j]; t[j] = t[j - 1]; t[j - 1] = tmp; }
    }
  }
}

// grid: (64 q, 6 src). src: 0=oh_d1 1=ins_d1 2=sen_d1 3=oh_d2 4=ins_d2 5=sen_d2
// sims order: 0=ins_d1 1=ins_d2 2=sen_d1 3=sen_d2, each [Q][D] row-major.
__global__ __launch_bounds__(256) void kmax_pool(
    const float* __restrict__ d1sim, const float* __restrict__ d2sim,
    const float* __restrict__ sims, float* __restrict__ pool) {
  int q = blockIdx.x, src = blockIdx.y;
  int tid = threadIdx.x;
  const size_t QD = (size_t)QQ * DD;
  float t5[5];
  #pragma unroll
  for (int j = 0; j < 5; ++j) t5[j] = -1e30f;
  for (int l = tid; l < DD; l += 256) {
    float v;
    switch (src) {
      case 0: v = d1sim[(size_t)l * QQ + q]; break;
      case 1: v = sims[0 * QD + (size_t)q * DD + l]; break;
      case 2: v = sims[2 * QD + (size_t)q * DD + l]; break;
      case 3: v = d2sim[(size_t)l * QQ + q]; break;
      case 4: v = sims[1 * QD + (size_t)q * DD + l]; break;
      default: v = sims[3 * QD + (size_t)q * DD + l]; break;
    }
    top5_insert(t5, v);
  }
  __shared__ float ls[256][5];
  #pragma unroll
  for (int j = 0; j < 5; ++j) ls[tid][j] = t5[j];
  __syncthreads();
  for (int step = 128; step >= 1; step >>= 1) {
    if (tid < step) {
      float a[5], c[5], m[5];
      #pragma unroll
      for (int j = 0; j < 5; ++j) { a[j] = ls[tid][j]; c[j] = ls[tid + step][j]; }
      int ia = 0, ib = 0;
      #pragma unroll
      for (int j = 0; j < 5; ++j) m[j] = (a[ia] >= c[ib]) ? a[ia++] : c[ib++];
      #pragma unroll
      for (int j = 0; j < 5; ++j) ls[tid][j] = m[j];
    }
    __syncthreads();
  }
  if (tid == 0) {
    float mx = ls[0][0];
    float sm = 0.f;
    #pragma unroll
    for (int j = 0; j < 5; ++j) sm += ls[0][j];
    pool[((size_t)src * QQ + q) * 2 + 0] = mx;
    pool[((size_t)src * QQ + q) * 2 + 1] = sm * 0.2f;
  }
}

// -------- final: qw + softmax + MLP + epilogue (one wave) --------
__global__ void final_kernel(
    const float* __restrict__ qconv, const float* __restrict__ idf,
    const int* __restrict__ question, const float* __restrict__ qw_w,
    const float* __restrict__ qw_b, const float* __restrict__ pool,
    const float* __restrict__ lin1_w, const float* __restrict__ lin2_w,
    const float* __restrict__ out_w, const float* __restrict__ gaf,
    const float* __restrict__ baf, float* __restrict__ out5) {
  int q = threadIdx.x;  // 64 threads = one wave
  const float* row = qconv + (size_t)q * EP;
  float s = qw_b[0];
  for (int i = 0; i < EE; ++i) s += row[i] * qw_w[i];
  s += idf[question[q]] * qw_w[EE];
  float m = s;
  #pragma unroll
  for (int o = 32; o; o >>= 1) m = fmaxf(m, __shfl_xor(m, o));
  float e = expf(s - m);
  float se = e;
  #pragma unroll
  for (int o = 32; o; o >>= 1) se += __shfl_xor(se, o);
  float qwgt = e / se;

  float emit[2];
  for (int doc = 0; doc < 2; ++doc) {
    float temp[6];
    #pragma unroll
    for (int j = 0; j < 3; ++j) {
      temp[2 * j]     = pool[(((size_t)doc * 3 + j) * QQ + q) * 2 + 0];
      temp[2 * j + 1] = pool[(((size_t)doc * 3 + j) * QQ + q) * 2 + 1];
    }
    float lo = 0.f;
    #pragma unroll
    for (int r = 0; r < 8; ++r) {
      float h = 0.f;
      #pragma unroll
      for (int c = 0; c < 6; ++c) h += lin1_w[r * 6 + c] * temp[c];
      h = (h >= 0.f) ? h : NEG * h;
      lo += lin2_w[r] * h;
    }
    lo *= qwgt;
    #pragma unroll
    for (int o = 32; o; o >>= 1) lo += __shfl_xor(lo, o);
    emit[doc] = lo / (float)QQ;
  }
  if (q == 0) {
    float good = out_w[0] * gaf[0] + out_w[1] * gaf[1] + out_w[2] * gaf[2] +
                 out_w[3] * gaf[3] + out_w[4] * emit[0];
    float bad  = out_w[0] * baf[0] + out_w[1] * baf[1] + out_w[2] * baf[2] +
                 out_w[3] * baf[3] + out_w[4] * emit[1];
    float l1 = fmaxf(0.f, -(good - bad) + 1.f);
    out5[0] = l1; out5[1] = good; out5[2] = bad; out5[3] = l1; out5[4] = l1;
  }
}

extern "C" void kernel_launch(void* const* d_in, const int* in_sizes, int n_in,
                              void* d_out, int out_size, void* d_ws, size_t ws_size,
                              hipStream_t stream) {
  (void)in_sizes; (void)n_in; (void)out_size; (void)ws_size;
  const int* question   = (const int*)d_in[0];
  const int* doc1       = (const int*)d_in[1];
  const int* doc2       = (const int*)d_in[2];
  const float* doc1_sim = (const float*)d_in[3];
  const float* doc2_sim = (const float*)d_in[4];
  const float* gaf      = (const float*)d_in[5];
  const float* baf      = (const float*)d_in[6];
  const float* emb      = (const float*)d_in[7];
  const float* idf      = (const float*)d_in[8];
  const float* conv_w   = (const float*)d_in[9];
  const float* conv_b   = (const float*)d_in[10];
  const float* qw_w     = (const float*)d_in[11];
  const float* qw_b     = (const float*)d_in[12];
  const float* lin1_w   = (const float*)d_in[13];
  const float* lin2_w   = (const float*)d_in[14];
  const float* out_w    = (const float*)d_in[15];
  float* out = (float*)d_out;

  float* p = (float*)d_ws;
  float* xq32 = p; p += QQ * EP;
  float* xd1  = p; p += (size_t)DD * EP;
  float* xd2  = p; p += (size_t)DD * EP;
  float* cq32 = p; p += QQ * EP;
  unsigned short* qbe  = (unsigned short*)p; p += (QQ + 2) * KP / 2;
  unsigned short* d1be = (unsigned short*)p; p += (size_t)(DD + 2) * KP / 2;
  unsigned short* d2be = (unsigned short*)p; p += (size_t)(DD + 2) * KP / 2;
  unsigned short* qbc  = (unsigned short*)p; p += QQ * KP / 2;
  unsigned short* d1bc = (unsigned short*)p; p += (size_t)DD * KP / 2;
  unsigned short* d2bc = (unsigned short*)p; p += (size_t)DD * KP / 2;
  unsigned short* wt   = (unsigned short*)p; p += 3 * EP * KP / 2;
  float* sims = p; p += (size_t)4 * QQ * DD;
  float* nq   = p; p += QQ;
  float* nd1  = p; p += DD;
  float* nd2  = p; p += DD;
  float* nqc  = p; p += QQ;
  float* nd1c = p; p += DD;
  float* nd2c = p; p += DD;
  float* pool = p; p += 6 * QQ * 2;

  gather_convert<<<dim3(DD + 2, 3), 64, 0, stream>>>(
      emb, question, doc1, doc2, xq32, xd1, xd2,
      qbe, d1be, d2be, qbc, d1bc, d2bc, nq, nd1, nd2);

  wtrans<<<dim3(EP, 3), 64, 0, stream>>>(conv_w, wt);

  conv_mfma<<<dim3(DD / 16, 3), 64, 0, stream>>>(
      wt, conv_b, qbe, d1be, d2be, xq32, xd1, xd2,
      qbc, d1bc, d2bc, cq32, nqc, nd1c, nd2c);

  sim_mfma<<<dim3(DD / 128, 4), 256, 0, stream>>>(
      qbe, d1be, d2be, qbc, d1bc, d2bc,
      nq, nd1, nd2, nqc, nd1c, nd2c, sims);

  kmax_pool<<<dim3(QQ, 6), 256, 0, stream>>>(doc1_sim, doc2_sim, sims, pool);

  final_kernel<<<1, 64, 0, stream>>>(cq32, idf, question, qw_w, qw_b, pool,
                                     lin1_w, lin2_w, out_w, gaf, baf, out);
}

// Round 3
// 72.822 us; speedup vs baseline: 7.9371x; 2.2279x over previous
//
#include <hip/hip_runtime.h>
#include <math.h>

#define EE 300
#define KP 320     // bf16 row stride (10 k-steps of 32)
#define LDSW 328   // padded LDS row stride in shorts (656 B -> bank-group stride 4)
#define QQ 64
#define DD 4096
#define NEG 0.01f

typedef __attribute__((ext_vector_type(8))) short short8;
typedef __attribute__((ext_vector_type(4))) float f32x4;
typedef unsigned short ushort_t;

__device__ inline ushort_t f2bf(float f) {
  unsigned u = __builtin_bit_cast(unsigned, f);
  u += 0x7fff + ((u >> 16) & 1);   // RNE
  return (ushort_t)(u >> 16);
}
__device__ inline float bf2f(ushort_t h) {
  return __builtin_bit_cast(float, (unsigned)h << 16);
}

// -------- gather emb rows -> guarded bf16 rows + emb row norms --------
__global__ __launch_bounds__(64) void gather_convert(
    const float* __restrict__ emb, const int* __restrict__ question,
    const int* __restrict__ doc1, const int* __restrict__ doc2,
    ushort_t* __restrict__ qbe, ushort_t* __restrict__ d1be, ushort_t* __restrict__ d2be,
    ushort_t* __restrict__ qbc, ushort_t* __restrict__ d1bc, ushort_t* __restrict__ d2bc,
    float* __restrict__ nq, float* __restrict__ nd1, float* __restrict__ nd2) {
  int t = blockIdx.y;
  const int* idx = t == 0 ? question : (t == 1 ? doc1 : doc2);
  int L = t == 0 ? QQ : DD;
  ushort_t* be = t == 0 ? qbe : (t == 1 ? d1be : d2be);
  ushort_t* bc = t == 0 ? qbc : (t == 1 ? d1bc : d2bc);
  float* nrm = t == 0 ? nq : (t == 1 ? nd1 : nd2);
  int row = blockIdx.x;
  if (row >= L + 2) return;
  int lane = threadIdx.x;
  if (row == 0 || row == L + 1) {            // zero guard rows
    for (int i = lane; i < KP; i += 64) be[(size_t)row * KP + i] = 0;
    return;
  }
  int r = row - 1;
  const float* src = emb + (size_t)idx[r] * EE;
  float ss = 0.f;
  for (int i = lane; i < EE; i += 64) {
    float v = src[i];
    be[(size_t)row * KP + i] = f2bf(v);
    ss += v * v;
  }
  for (int i = EE + lane; i < KP; i += 64) {  // zero K-pads (be and conv-out)
    be[(size_t)row * KP + i] = 0;
    bc[(size_t)r * KP + i] = 0;
  }
  #pragma unroll
  for (int o = 32; o; o >>= 1) ss += __shfl_xor(ss, o);
  if (lane == 0) nrm[r] = sqrtf(ss);
}

// -------- weights -> fragment-major bf16: wt2[(tap*19+n)*10+ks][lane][8] --------
// B-frag for 16x16x32: lane l holds B[k = ks*32+(l>>4)*8+e][col = n*16+(l&15)]
__global__ __launch_bounds__(64) void wtrans2(const float* __restrict__ w,
                                              ushort_t* __restrict__ wt2) {
  int f = blockIdx.x;                 // 0..569
  int ks = f % 10, n = (f / 10) % 19, tap = f / 190;
  int lane = threadIdx.x;
  int o = n * 16 + (lane & 15);
  int kbase = ks * 32 + (lane >> 4) * 8;
  ushort_t* dst = wt2 + (size_t)f * 512 + lane * 8;
  #pragma unroll
  for (int e = 0; e < 8; ++e) {
    int k = kbase + e;
    float v = (o < EE && k < EE) ? w[((size_t)o * EE + k) * 3 + tap] : 0.f;
    dst[e] = f2bf(v);
  }
}

// -------- conv1d(E,E,3,SAME)+bias+leaky+residual: 3 shifted bf16 MFMA GEMMs --------
// Block: 256 thr = 4 waves, one 32-row M-tile, N-half per blockIdx.y.
// A-tile (34 guarded rows) staged in padded LDS; B 1KB-coalesced from wt2.
__global__ __launch_bounds__(256) void conv_mfma(
    const ushort_t* __restrict__ wt2, const float* __restrict__ bias,
    const ushort_t* __restrict__ qbe, const ushort_t* __restrict__ d1be,
    const ushort_t* __restrict__ d2be,
    ushort_t* __restrict__ qbc, ushort_t* __restrict__ d1bc,
    ushort_t* __restrict__ d2bc) {
  __shared__ ushort_t lds[34 * LDSW];
  int mt = blockIdx.x;
  int t, m0;
  if (mt < 2)        { t = 0; m0 = mt * 32; }
  else if (mt < 130) { t = 1; m0 = (mt - 2) * 32; }
  else               { t = 2; m0 = (mt - 130) * 32; }
  const ushort_t* be = t == 0 ? qbe : (t == 1 ? d1be : d2be);
  ushort_t* bc = t == 0 ? qbc : (t == 1 ? d1bc : d2bc);
  int tid = threadIdx.x;
  for (int s = tid; s < 34 * 40; s += 256) {
    int row = s / 40, col = s - row * 40;
    *(short8*)(&lds[row * LDSW + col * 8]) =
        *(const short8*)(be + (size_t)(m0 + row) * KP + col * 8);
  }
  __syncthreads();
  int w = tid >> 6, lane = tid & 63, mrow = lane & 15, g = lane >> 4;
  int nstart, ncnt;
  if (blockIdx.y == 0) { nstart = (w < 2) ? 3 * w : 2 * w + 2; ncnt = (w < 2) ? 3 : 2; }
  else                 { nstart = (w == 0) ? 10 : 2 * w + 11;  ncnt = (w == 0) ? 3 : 2; }
  f32x4 acc[3][2];
  #pragma unroll
  for (int j = 0; j < 3; ++j)
    #pragma unroll
    for (int h = 0; h < 2; ++h) acc[j][h] = (f32x4){0.f, 0.f, 0.f, 0.f};

  for (int tap = 0; tap < 3; ++tap) {
    const ushort_t* alo = &lds[(mrow + tap) * LDSW + g * 8];
    #pragma unroll
    for (int ks = 0; ks < 10; ++ks) {
      short8 a0 = *(const short8*)(alo + ks * 32);
      short8 a1 = *(const short8*)(alo + 16 * LDSW + ks * 32);
      #pragma unroll
      for (int j = 0; j < 3; ++j) {
        if (j < ncnt) {
          short8 b = *(const short8*)(wt2 +
              (size_t)((tap * 19 + nstart + j) * 10 + ks) * 512 + lane * 8);
          acc[j][0] = __builtin_amdgcn_mfma_f32_16x16x32_bf16(a0, b, acc[j][0], 0, 0, 0);
          acc[j][1] = __builtin_amdgcn_mfma_f32_16x16x32_bf16(a1, b, acc[j][1], 0, 0, 0);
        }
      }
    }
  }
  // C layout: col = lane&15 (output channel), row = g*4 + r within 16-row half
  #pragma unroll
  for (int j = 0; j < 3; ++j) {
    if (j < ncnt) {
      int col = (nstart + j) * 16 + mrow;
      if (col < EE) {
        float bcol = bias[col];
        #pragma unroll
        for (int h = 0; h < 2; ++h) {
          #pragma unroll
          for (int r = 0; r < 4; ++r) {
            int lrow = h * 16 + g * 4 + r;     // 0..31
            float y = acc[j][h][r] + bcol;
            y = (y >= 0.f) ? y : NEG * y;
            y += bf2f(lds[(1 + lrow) * LDSW + col]);   // residual x[m0+lrow]
            bc[(size_t)(m0 + lrow) * KP + col] = f2bf(y);
          }
        }
      }
    }
  }
}

// -------- conv-output row norms (bf16 rows, zero-padded to KP) --------
__global__ __launch_bounds__(256) void row_norms_bf16(
    const ushort_t* __restrict__ qbc, const ushort_t* __restrict__ d1bc,
    const ushort_t* __restrict__ d2bc,
    float* __restrict__ nqc, float* __restrict__ nd1c, float* __restrict__ nd2c) {
  int t = blockIdx.y;
  const ushort_t* x = t == 0 ? qbc : (t == 1 ? d1bc : d2bc);
  float* nrm = t == 0 ? nqc : (t == 1 ? nd1c : nd2c);
  int L = t == 0 ? QQ : DD;
  int wid = blockIdx.x * 4 + (threadIdx.x >> 6);
  if (wid >= L) return;
  int lane = threadIdx.x & 63;
  float ss = 0.f;
  if (lane < 38) {
    short8 v = *(const short8*)(x + (size_t)wid * KP + lane * 8);
    #pragma unroll
    for (int e = 0; e < 8; ++e) { float f = bf2f((ushort_t)v[e]); ss += f * f; }
  }
  #pragma unroll
  for (int o = 32; o; o >>= 1) ss += __shfl_xor(ss, o);
  if (lane == 0) nrm[wid] = sqrtf(ss);
}

// -------- cosine sims as bf16 MFMA GEMM; B-tile (32 l-rows) LDS-staged --------
// grid (DD/32, 4 sims), 256 thr: wave w = q-tile, 2 l-tiles of 16 each.
__global__ __launch_bounds__(256) void sim_mfma(
    const ushort_t* __restrict__ qbe, const ushort_t* __restrict__ d1be,
    const ushort_t* __restrict__ d2be,
    const ushort_t* __restrict__ qbc, const ushort_t* __restrict__ d1bc,
    const ushort_t* __restrict__ d2bc,
    const float* __restrict__ nq, const float* __restrict__ nd1,
    const float* __restrict__ nd2, const float* __restrict__ nqc,
    const float* __restrict__ nd1c, const float* __restrict__ nd2c,
    float* __restrict__ sims) {
  __shared__ ushort_t lds[32 * LDSW];
  int s = blockIdx.y;
  const ushort_t* A = (s < 2) ? qbe + KP : qbc;    // skip guard row
  const ushort_t* B = s == 0 ? d1be + KP : s == 1 ? d2be + KP : s == 2 ? d1bc : d2bc;
  const float* na = (s < 2) ? nq : nqc;
  const float* nb = s == 0 ? nd1 : s == 1 ? nd2 : s == 2 ? nd1c : nd2c;
  float* out = sims + (size_t)s * QQ * DD;
  int l0 = blockIdx.x * 32;
  int tid = threadIdx.x;
  for (int i = tid; i < 32 * 40; i += 256) {
    int row = i / 40, col = i - row * 40;
    *(short8*)(&lds[row * LDSW + col * 8]) =
        *(const short8*)(B + (size_t)(l0 + row) * KP + col * 8);
  }
  __syncthreads();
  int w = tid >> 6, lane = tid & 63, mrow = lane & 15, g = lane >> 4;
  f32x4 acc[2];
  acc[0] = (f32x4){0.f, 0.f, 0.f, 0.f};
  acc[1] = (f32x4){0.f, 0.f, 0.f, 0.f};
  const ushort_t* arow = A + (size_t)(w * 16 + mrow) * KP + g * 8;
  #pragma unroll
  for (int ks = 0; ks < 10; ++ks) {
    short8 a = *(const short8*)(arow + ks * 32);
    #pragma unroll
    for (int n = 0; n < 2; ++n) {
      short8 b = *(const short8*)(&lds[(n * 16 + mrow) * LDSW + g * 8 + ks * 32]);
      acc[n] = __builtin_amdgcn_mfma_f32_16x16x32_bf16(a, b, acc[n], 0, 0, 0);
    }
  }
  #pragma unroll
  for (int n = 0; n < 2; ++n) {
    int l = l0 + n * 16 + mrow;
    float inb = 1.f / nb[l];
    #pragma unroll
    for (int r = 0; r < 4; ++r) {
      int q = w * 16 + g * 4 + r;
      out[(size_t)q * DD + l] = acc[n][r] / na[q] * inb;
    }
  }
}

// -------- top-5 pooling --------
__device__ inline void top5_insert(float* t, float v) {
  if (v > t[4]) {
    t[4] = v;
    #pragma unroll
    for (int j = 4; j > 0; --j) {
      if (t[j] > t[j - 1]) { float tmp = t[j]; t[j] = t[j - 1]; t[j - 1] = tmp; }
    }
  }
}

// grid: (64 q, 6 src). sims order: 0=ins_d1 1=ins_d2 2=sen_d1 3=sen_d2
__global__ __launch_bounds__(256) void kmax_pool(
    const float* __restrict__ d1sim, const float* __restrict__ d2sim,
    const float* __restrict__ sims, float* __restrict__ pool) {
  int q = blockIdx.x, src = blockIdx.y;
  int tid = threadIdx.x;
  const size_t QD = (size_t)QQ * DD;
  float t5[5];
  #pragma unroll
  for (int j = 0; j < 5; ++j) t5[j] = -1e30f;
  for (int l = tid; l < DD; l += 256) {
    float v;
    switch (src) {
      case 0: v = d1sim[(size_t)l * QQ + q]; break;
      case 1: v = sims[0 * QD + (size_t)q * DD + l]; break;
      case 2: v = sims[2 * QD + (size_t)q * DD + l]; break;
      case 3: v = d2sim[(size_t)l * QQ + q]; break;
      case 4: v = sims[1 * QD + (size_t)q * DD + l]; break;
      default: v = sims[3 * QD + (size_t)q * DD + l]; break;
    }
    top5_insert(t5, v);
  }
  __shared__ float ls[256][5];
  #pragma unroll
  for (int j = 0; j < 5; ++j) ls[tid][j] = t5[j];
  __syncthreads();
  for (int step = 128; step >= 1; step >>= 1) {
    if (tid < step) {
      float a[5], c[5], m[5];
      #pragma unroll
      for (int j = 0; j < 5; ++j) { a[j] = ls[tid][j]; c[j] = ls[tid + step][j]; }
      int ia = 0, ib = 0;
      #pragma unroll
      for (int j = 0; j < 5; ++j) m[j] = (a[ia] >= c[ib]) ? a[ia++] : c[ib++];
      #pragma unroll
      for (int j = 0; j < 5; ++j) ls[tid][j] = m[j];
    }
    __syncthreads();
  }
  if (tid == 0) {
    float mx = ls[0][0];
    float sm = 0.f;
    #pragma unroll
    for (int j = 0; j < 5; ++j) sm += ls[0][j];
    pool[((size_t)src * QQ + q) * 2 + 0] = mx;
    pool[((size_t)src * QQ + q) * 2 + 1] = sm * 0.2f;
  }
}

// -------- final: qw + softmax + MLP + epilogue (one wave) --------
__global__ void final_kernel(
    const ushort_t* __restrict__ qbc, const float* __restrict__ idf,
    const int* __restrict__ question, const float* __restrict__ qw_w,
    const float* __restrict__ qw_b, const float* __restrict__ pool,
    const float* __restrict__ lin1_w, const float* __restrict__ lin2_w,
    const float* __restrict__ out_w, const float* __restrict__ gaf,
    const float* __restrict__ baf, float* __restrict__ out5) {
  int q = threadIdx.x;  // 64 threads = one wave
  const ushort_t* row = qbc + (size_t)q * KP;
  float s = qw_b[0];
  for (int i8 = 0; i8 < 37; ++i8) {
    short8 v = *(const short8*)(row + i8 * 8);
    #pragma unroll
    for (int e = 0; e < 8; ++e) s += bf2f((ushort_t)v[e]) * qw_w[i8 * 8 + e];
  }
  for (int i = 296; i < EE; ++i) s += bf2f(row[i]) * qw_w[i];
  s += idf[question[q]] * qw_w[EE];
  float m = s;
  #pragma unroll
  for (int o = 32; o; o >>= 1) m = fmaxf(m, __shfl_xor(m, o));
  float e = expf(s - m);
  float se = e;
  #pragma unroll
  for (int o = 32; o; o >>= 1) se += __shfl_xor(se, o);
  float qwgt = e / se;

  float emit[2];
  for (int doc = 0; doc < 2; ++doc) {
    float temp[6];
    #pragma unroll
    for (int j = 0; j < 3; ++j) {
      temp[2 * j]     = pool[(((size_t)doc * 3 + j) * QQ + q) * 2 + 0];
      temp[2 * j + 1] = pool[(((size_t)doc * 3 + j) * QQ + q) * 2 + 1];
    }
    float lo = 0.f;
    #pragma unroll
    for (int r = 0; r < 8; ++r) {
      float h = 0.f;
      #pragma unroll
      for (int c = 0; c < 6; ++c) h += lin1_w[r * 6 + c] * temp[c];
      h = (h >= 0.f) ? h : NEG * h;
      lo += lin2_w[r] * h;
    }
    lo *= qwgt;
    #pragma unroll
    for (int o = 32; o; o >>= 1) lo += __shfl_xor(lo, o);
    emit[doc] = lo / (float)QQ;
  }
  if (q == 0) {
    float good = out_w[0] * gaf[0] + out_w[1] * gaf[1] + out_w[2] * gaf[2] +
                 out_w[3] * gaf[3] + out_w[4] * emit[0];
    float bad  = out_w[0] * baf[0] + out_w[1] * baf[1] + out_w[2] * baf[2] +
                 out_w[3] * baf[3] + out_w[4] * emit[1];
    float l1 = fmaxf(0.f, -(good - bad) + 1.f);
    out5[0] = l1; out5[1] = good; out5[2] = bad; out5[3] = l1; out5[4] = l1;
  }
}

extern "C" void kernel_launch(void* const* d_in, const int* in_sizes, int n_in,
                              void* d_out, int out_size, void* d_ws, size_t ws_size,
                              hipStream_t stream) {
  (void)in_sizes; (void)n_in; (void)out_size; (void)ws_size;
  const int* question   = (const int*)d_in[0];
  const int* doc1       = (const int*)d_in[1];
  const int* doc2       = (const int*)d_in[2];
  const float* doc1_sim = (const float*)d_in[3];
  const float* doc2_sim = (const float*)d_in[4];
  const float* gaf      = (const float*)d_in[5];
  const float* baf      = (const float*)d_in[6];
  const float* emb      = (const float*)d_in[7];
  const float* idf      = (const float*)d_in[8];
  const float* conv_w   = (const float*)d_in[9];
  const float* conv_b   = (const float*)d_in[10];
  const float* qw_w     = (const float*)d_in[11];
  const float* qw_b     = (const float*)d_in[12];
  const float* lin1_w   = (const float*)d_in[13];
  const float* lin2_w   = (const float*)d_in[14];
  const float* out_w    = (const float*)d_in[15];
  float* out = (float*)d_out;

  char* p = (char*)d_ws;
  ushort_t* qbe  = (ushort_t*)p; p += (size_t)(QQ + 2) * KP * 2;
  ushort_t* d1be = (ushort_t*)p; p += (size_t)(DD + 2) * KP * 2;
  ushort_t* d2be = (ushort_t*)p; p += (size_t)(DD + 2) * KP * 2;
  ushort_t* qbc  = (ushort_t*)p; p += (size_t)QQ * KP * 2;
  ushort_t* d1bc = (ushort_t*)p; p += (size_t)DD * KP * 2;
  ushort_t* d2bc = (ushort_t*)p; p += (size_t)DD * KP * 2;
  ushort_t* wt2  = (ushort_t*)p; p += (size_t)570 * 512 * 2;
  float* sims = (float*)p; p += (size_t)4 * QQ * DD * 4;
  float* nq   = (float*)p; p += QQ * 4;
  float* nd1  = (float*)p; p += DD * 4;
  float* nd2  = (float*)p; p += DD * 4;
  float* nqc  = (float*)p; p += QQ * 4;
  float* nd1c = (float*)p; p += DD * 4;
  float* nd2c = (float*)p; p += DD * 4;
  float* pool = (float*)p; p += 6 * QQ * 2 * 4;

  gather_convert<<<dim3(DD + 2, 3), 64, 0, stream>>>(
      emb, question, doc1, doc2, qbe, d1be, d2be, qbc, d1bc, d2bc, nq, nd1, nd2);

  wtrans2<<<570, 64, 0, stream>>>(conv_w, wt2);

  conv_mfma<<<dim3(258, 2), 256, 0, stream>>>(
      wt2, conv_b, qbe, d1be, d2be, qbc, d1bc, d2bc);

  row_norms_bf16<<<dim3(DD / 4, 3), 256, 0, stream>>>(
      qbc, d1bc, d2bc, nqc, nd1c, nd2c);

  sim_mfma<<<dim3(DD / 32, 4), 256, 0, stream>>>(
      qbe, d1be, d2be, qbc, d1bc, d2bc,
      nq, nd1, nd2, nqc, nd1c, nd2c, sims);

  kmax_pool<<<dim3(QQ, 6), 256, 0, stream>>>(doc1_sim, doc2_sim, sims, pool);

  final_kernel<<<1, 64, 0, stream>>>(qbc, idf, question, qw_w, qw_b, pool,
                                     lin1_w, lin2_w, out_w, gaf, baf, out);
}

// Round 4
// 62.104 us; speedup vs baseline: 9.3068x; 1.1726x over previous
//
#include <hip/hip_runtime.h>
#include <math.h>

#define EE 300
#define KP 320     // bf16 row stride (10 k-steps of 32)
#define LDSW 328   // padded LDS row stride in shorts
#define QQ 64
#define DD 4096
#define NEG 0.01f

typedef __attribute__((ext_vector_type(8))) short short8;
typedef __attribute__((ext_vector_type(4))) float f32x4;
typedef unsigned short ushort_t;

__device__ inline ushort_t f2bf(float f) {
  unsigned u = __builtin_bit_cast(unsigned, f);
  u += 0x7fff + ((u >> 16) & 1);   // RNE
  return (ushort_t)(u >> 16);
}
__device__ inline float bf2f(ushort_t h) {
  return __builtin_bit_cast(float, (unsigned)h << 16);
}

// ================= prep: gather+convert | wtrans | oh transpose | zero =======
#define GATHER_ROWS (66 + 4098 + 4098)           // 8262
#define GATHER_BLOCKS ((GATHER_ROWS + 3) / 4)    // 2066
#define WT_BLOCKS 143                            // 570 frags / 4
#define TR_BLOCKS 128                            // 64 tiles x 2 srcs
#define ZERO_BLOCKS 9                            // 8320 floats
#define PREP_BLOCKS (GATHER_BLOCKS + WT_BLOCKS + TR_BLOCKS + ZERO_BLOCKS)

__global__ __launch_bounds__(256) void prep(
    const float* __restrict__ emb, const int* __restrict__ question,
    const int* __restrict__ doc1, const int* __restrict__ doc2,
    const float* __restrict__ conv_w,
    const float* __restrict__ doc1_sim, const float* __restrict__ doc2_sim,
    ushort_t* __restrict__ qbe, ushort_t* __restrict__ d1be, ushort_t* __restrict__ d2be,
    ushort_t* __restrict__ qbc, ushort_t* __restrict__ d1bc, ushort_t* __restrict__ d2bc,
    ushort_t* __restrict__ wt2,
    float* __restrict__ ohT1, float* __restrict__ ohT2,
    float* __restrict__ nq2, float* __restrict__ nd12, float* __restrict__ nd22,
    float* __restrict__ acc_zero_base) {
  __shared__ float tilebuf[64][65];
  int b = blockIdx.x;
  int tid = threadIdx.x;
  if (b < GATHER_BLOCKS) {
    int w = tid >> 6, lane = tid & 63;
    int g = b * 4 + w;
    int t, row;
    if (g < 66)             { t = 0; row = g; }
    else if (g < 66 + 4098) { t = 1; row = g - 66; }
    else if (g < GATHER_ROWS) { t = 2; row = g - 66 - 4098; }
    else return;
    const int* idx = t == 0 ? question : (t == 1 ? doc1 : doc2);
    int L = t == 0 ? QQ : DD;
    ushort_t* be = t == 0 ? qbe : (t == 1 ? d1be : d2be);
    ushort_t* bc = t == 0 ? qbc : (t == 1 ? d1bc : d2bc);
    float* nrm2 = t == 0 ? nq2 : (t == 1 ? nd12 : nd22);
    if (row == 0 || row == L + 1) {          // zero guard rows
      for (int i = lane; i < KP; i += 64) be[(size_t)row * KP + i] = 0;
      return;
    }
    int r = row - 1;
    const float* src = emb + (size_t)idx[r] * EE;
    float ss = 0.f;
    for (int i = lane; i < EE; i += 64) {
      float v = src[i];
      be[(size_t)row * KP + i] = f2bf(v);
      ss += v * v;
    }
    for (int i = EE + lane; i < KP; i += 64) {   // zero K-pads
      be[(size_t)row * KP + i] = 0;
      bc[(size_t)r * KP + i] = 0;
    }
    #pragma unroll
    for (int o = 32; o; o >>= 1) ss += __shfl_xor(ss, o);
    if (lane == 0) nrm2[r] = ss;                 // SQUARED norm
  } else if (b < GATHER_BLOCKS + WT_BLOCKS) {
    int f = (b - GATHER_BLOCKS) * 4 + (tid >> 6);
    if (f >= 570) return;
    int lane = tid & 63;
    int ks = f % 10, n = (f / 10) % 19, tap = f / 190;
    int o = n * 16 + (lane & 15);
    int kbase = ks * 32 + (lane >> 4) * 8;
    ushort_t* dst = wt2 + (size_t)f * 512 + lane * 8;
    #pragma unroll
    for (int e = 0; e < 8; ++e) {
      int k = kbase + e;
      float v = (o < EE && k < EE) ? conv_w[((size_t)o * EE + k) * 3 + tap] : 0.f;
      dst[e] = f2bf(v);
    }
  } else if (b < GATHER_BLOCKS + WT_BLOCKS + TR_BLOCKS) {
    int idx = b - (GATHER_BLOCKS + WT_BLOCKS);
    int srcsel = idx >> 6, tile = idx & 63;
    const float* in = srcsel ? doc2_sim : doc1_sim;   // [D][Q]
    float* outT = srcsel ? ohT2 : ohT1;               // [Q][D]
    int c = tid & 63, rq = tid >> 6;
    #pragma unroll 4
    for (int i = 0; i < 16; ++i) {
      int r = i * 4 + rq;
      tilebuf[r][c] = in[(size_t)(tile * 64 + r) * QQ + c];
    }
    __syncthreads();
    #pragma unroll 4
    for (int i = 0; i < 16; ++i) {
      int q = i * 4 + rq;
      outT[(size_t)q * DD + tile * 64 + c] = tilebuf[c][q];
    }
  } else {
    int i0 = (b - (GATHER_BLOCKS + WT_BLOCKS + TR_BLOCKS)) * 1024 + tid;
    #pragma unroll
    for (int j = 0; j < 4; ++j) {
      int i = i0 + j * 256;
      if (i < 8320) acc_zero_base[i] = 0.f;
    }
  }
}

// ===== conv1d(E,E,3,SAME)+bias+leaky+residual, fused norms^2 + qw-dot =======
// 516 blocks: bx<4 -> question (2 m-tiles x 2 n-halves); else docs.
__global__ __launch_bounds__(256) void conv_mfma(
    const ushort_t* __restrict__ wt2, const float* __restrict__ bias,
    const float* __restrict__ qw_w,
    const ushort_t* __restrict__ qbe, const ushort_t* __restrict__ d1be,
    const ushort_t* __restrict__ d2be,
    ushort_t* __restrict__ qbc, ushort_t* __restrict__ d1bc,
    ushort_t* __restrict__ d2bc,
    float* __restrict__ nqc2, float* __restrict__ nd1c2, float* __restrict__ nd2c2,
    float* __restrict__ qwacc) {
  __shared__ ushort_t lds[34 * LDSW];
  int bx = blockIdx.x;
  int t, m0, yh;
  if (bx < 4) { t = 0; m0 = (bx >> 1) * 32; yh = bx & 1; }
  else {
    int i = bx - 4;
    t = 1 + (i >> 8);
    int j = i & 255;
    m0 = (j >> 1) * 32; yh = j & 1;
  }
  const ushort_t* be = t == 0 ? qbe : (t == 1 ? d1be : d2be);
  ushort_t* bc = t == 0 ? qbc : (t == 1 ? d1bc : d2bc);
  float* nc2 = t == 0 ? nqc2 : (t == 1 ? nd1c2 : nd2c2);
  int tid = threadIdx.x;
  for (int s = tid; s < 34 * 40; s += 256) {
    int row = s / 40, col = s - row * 40;
    *(short8*)(&lds[row * LDSW + col * 8]) =
        *(const short8*)(be + (size_t)(m0 + row) * KP + col * 8);
  }
  __syncthreads();
  int w = tid >> 6, lane = tid & 63, mrow = lane & 15, g = lane >> 4;
  int nstart, ncnt;
  if (yh == 0) { nstart = (w < 2) ? 3 * w : 2 * w + 2; ncnt = (w < 2) ? 3 : 2; }
  else         { nstart = (w == 0) ? 10 : 2 * w + 11;  ncnt = (w == 0) ? 3 : 2; }
  f32x4 acc[3][2];
  #pragma unroll
  for (int j = 0; j < 3; ++j)
    #pragma unroll
    for (int h = 0; h < 2; ++h) acc[j][h] = (f32x4){0.f, 0.f, 0.f, 0.f};

  for (int tap = 0; tap < 3; ++tap) {
    const ushort_t* alo = &lds[(mrow + tap) * LDSW + g * 8];
    #pragma unroll
    for (int ks = 0; ks < 10; ++ks) {
      short8 a0 = *(const short8*)(alo + ks * 32);
      short8 a1 = *(const short8*)(alo + 16 * LDSW + ks * 32);
      #pragma unroll
      for (int j = 0; j < 3; ++j) {
        if (j < ncnt) {
          short8 bfr = *(const short8*)(wt2 +
              (size_t)((tap * 19 + nstart + j) * 10 + ks) * 512 + lane * 8);
          acc[j][0] = __builtin_amdgcn_mfma_f32_16x16x32_bf16(a0, bfr, acc[j][0], 0, 0, 0);
          acc[j][1] = __builtin_amdgcn_mfma_f32_16x16x32_bf16(a1, bfr, acc[j][1], 0, 0, 0);
        }
      }
    }
  }
  // epilogue: col = n*16 + mrow, row = m0 + h*16 + g*4 + r
  float ss[2][4] = {{0.f,0.f,0.f,0.f},{0.f,0.f,0.f,0.f}};
  float yq[2][4] = {{0.f,0.f,0.f,0.f},{0.f,0.f,0.f,0.f}};
  #pragma unroll
  for (int j = 0; j < 3; ++j) {
    if (j < ncnt) {
      int col = (nstart + j) * 16 + mrow;
      if (col < EE) {
        float bcol = bias[col];
        float qwc = (t == 0) ? qw_w[col] : 0.f;
        #pragma unroll
        for (int h = 0; h < 2; ++h) {
          #pragma unroll
          for (int r = 0; r < 4; ++r) {
            int lrow = h * 16 + g * 4 + r;
            float y = acc[j][h][r] + bcol;
            y = (y >= 0.f) ? y : NEG * y;
            y += bf2f(lds[(1 + lrow) * LDSW + col]);
            bc[(size_t)(m0 + lrow) * KP + col] = f2bf(y);
            ss[h][r] += y * y;
            if (t == 0) yq[h][r] += y * qwc;
          }
        }
      }
    }
  }
  #pragma unroll
  for (int h = 0; h < 2; ++h) {
    #pragma unroll
    for (int r = 0; r < 4; ++r) {
      float s = ss[h][r];
      s += __shfl_xor(s, 1); s += __shfl_xor(s, 2);
      s += __shfl_xor(s, 4); s += __shfl_xor(s, 8);
      if (mrow == 0) atomicAdd(&nc2[m0 + h * 16 + g * 4 + r], s);
      if (t == 0) {
        float sq = yq[h][r];
        sq += __shfl_xor(sq, 1); sq += __shfl_xor(sq, 2);
        sq += __shfl_xor(sq, 4); sq += __shfl_xor(sq, 8);
        if (mrow == 0) atomicAdd(&qwacc[m0 + h * 16 + g * 4 + r], sq);
      }
    }
  }
}

// ======== cosine sims as bf16 MFMA GEMM; rsqrt of squared norms =============
__global__ __launch_bounds__(256) void sim_mfma(
    const ushort_t* __restrict__ qbe, const ushort_t* __restrict__ d1be,
    const ushort_t* __restrict__ d2be,
    const ushort_t* __restrict__ qbc, const ushort_t* __restrict__ d1bc,
    const ushort_t* __restrict__ d2bc,
    const float* __restrict__ nq2, const float* __restrict__ nd12,
    const float* __restrict__ nd22, const float* __restrict__ nqc2,
    const float* __restrict__ nd1c2, const float* __restrict__ nd2c2,
    float* __restrict__ sims) {
  __shared__ ushort_t lds[32 * LDSW];
  int s = blockIdx.y;
  const ushort_t* A = (s < 2) ? qbe + KP : qbc;
  const ushort_t* B = s == 0 ? d1be + KP : s == 1 ? d2be + KP : s == 2 ? d1bc : d2bc;
  const float* na2 = (s < 2) ? nq2 : nqc2;
  const float* nb2 = s == 0 ? nd12 : s == 1 ? nd22 : s == 2 ? nd1c2 : nd2c2;
  float* out = sims + (size_t)s * QQ * DD;
  int l0 = blockIdx.x * 32;
  int tid = threadIdx.x;
  for (int i = tid; i < 32 * 40; i += 256) {
    int row = i / 40, col = i - row * 40;
    *(short8*)(&lds[row * LDSW + col * 8]) =
        *(const short8*)(B + (size_t)(l0 + row) * KP + col * 8);
  }
  __syncthreads();
  int w = tid >> 6, lane = tid & 63, mrow = lane & 15, g = lane >> 4;
  f32x4 acc[2];
  acc[0] = (f32x4){0.f, 0.f, 0.f, 0.f};
  acc[1] = (f32x4){0.f, 0.f, 0.f, 0.f};
  const ushort_t* arow = A + (size_t)(w * 16 + mrow) * KP + g * 8;
  #pragma unroll
  for (int ks = 0; ks < 10; ++ks) {
    short8 a = *(const short8*)(arow + ks * 32);
    #pragma unroll
    for (int n = 0; n < 2; ++n) {
      short8 bfr = *(const short8*)(&lds[(n * 16 + mrow) * LDSW + g * 8 + ks * 32]);
      acc[n] = __builtin_amdgcn_mfma_f32_16x16x32_bf16(a, bfr, acc[n], 0, 0, 0);
    }
  }
  #pragma unroll
  for (int n = 0; n < 2; ++n) {
    int l = l0 + n * 16 + mrow;
    float inb = rsqrtf(nb2[l]);
    #pragma unroll
    for (int r = 0; r < 4; ++r) {
      int q = w * 16 + g * 4 + r;
      out[(size_t)q * DD + l] = acc[n][r] * rsqrtf(na2[q]) * inb;
    }
  }
}

// ================= top-5 pooling (all srcs [Q][D] coalesced) ================
__device__ inline void top5_insert(float* t, float v) {
  if (v > t[4]) {
    t[4] = v;
    #pragma unroll
    for (int j = 4; j > 0; --j) {
      if (t[j] > t[j - 1]) { float tmp = t[j]; t[j] = t[j - 1]; t[j - 1] = tmp; }
    }
  }
}

__global__ __launch_bounds__(256) void kmax_pool(
    const float* __restrict__ ohT1, const float* __restrict__ ohT2,
    const float* __restrict__ sims, float* __restrict__ pool) {
  int q = blockIdx.x, src = blockIdx.y;
  int tid = threadIdx.x;
  const size_t QD = (size_t)QQ * DD;
  const float* base;
  switch (src) {
    case 0: base = ohT1; break;
    case 1: base = sims + 0 * QD; break;
    case 2: base = sims + 2 * QD; break;
    case 3: base = ohT2; break;
    case 4: base = sims + 1 * QD; break;
    default: base = sims + 3 * QD; break;
  }
  const float* row = base + (size_t)q * DD;
  float t5[5];
  #pragma unroll
  for (int j = 0; j < 5; ++j) t5[j] = -1e30f;
  for (int l = tid; l < DD; l += 256) top5_insert(t5, row[l]);
  __shared__ float ls[256][5];
  #pragma unroll
  for (int j = 0; j < 5; ++j) ls[tid][j] = t5[j];
  __syncthreads();
  for (int step = 128; step >= 1; step >>= 1) {
    if (tid < step) {
      float a[5], c[5], m[5];
      #pragma unroll
      for (int j = 0; j < 5; ++j) { a[j] = ls[tid][j]; c[j] = ls[tid + step][j]; }
      int ia = 0, ib = 0;
      #pragma unroll
      for (int j = 0; j < 5; ++j) m[j] = (a[ia] >= c[ib]) ? a[ia++] : c[ib++];
      #pragma unroll
      for (int j = 0; j < 5; ++j) ls[tid][j] = m[j];
    }
    __syncthreads();
  }
  if (tid == 0) {
    float mx = ls[0][0];
    float sm = 0.f;
    #pragma unroll
    for (int j = 0; j < 5; ++j) sm += ls[0][j];
    pool[((size_t)src * QQ + q) * 2 + 0] = mx;
    pool[((size_t)src * QQ + q) * 2 + 1] = sm * 0.2f;
  }
}

// ================= final: softmax + MLP + epilogue (one wave) ===============
__global__ void final_kernel(
    const float* __restrict__ qwacc, const float* __restrict__ idf,
    const int* __restrict__ question, const float* __restrict__ qw_w,
    const float* __restrict__ qw_b, const float* __restrict__ pool,
    const float* __restrict__ lin1_w, const float* __restrict__ lin2_w,
    const float* __restrict__ out_w, const float* __restrict__ gaf,
    const float* __restrict__ baf, float* __restrict__ out5) {
  int q = threadIdx.x;  // 64 threads = one wave
  float s = qwacc[q] + qw_b[0] + idf[question[q]] * qw_w[EE];
  float m = s;
  #pragma unroll
  for (int o = 32; o; o >>= 1) m = fmaxf(m, __shfl_xor(m, o));
  float e = expf(s - m);
  float se = e;
  #pragma unroll
  for (int o = 32; o; o >>= 1) se += __shfl_xor(se, o);
  float qwgt = e / se;

  float emit[2];
  for (int doc = 0; doc < 2; ++doc) {
    float temp[6];
    #pragma unroll
    for (int j = 0; j < 3; ++j) {
      temp[2 * j]     = pool[(((size_t)doc * 3 + j) * QQ + q) * 2 + 0];
      temp[2 * j + 1] = pool[(((size_t)doc * 3 + j) * QQ + q) * 2 + 1];
    }
    float lo = 0.f;
    #pragma unroll
    for (int r = 0; r < 8; ++r) {
      float h = 0.f;
      #pragma unroll
      for (int c = 0; c < 6; ++c) h += lin1_w[r * 6 + c] * temp[c];
      h = (h >= 0.f) ? h : NEG * h;
      lo += lin2_w[r] * h;
    }
    lo *= qwgt;
    #pragma unroll
    for (int o = 32; o; o >>= 1) lo += __shfl_xor(lo, o);
    emit[doc] = lo / (float)QQ;
  }
  if (q == 0) {
    float good = out_w[0] * gaf[0] + out_w[1] * gaf[1] + out_w[2] * gaf[2] +
                 out_w[3] * gaf[3] + out_w[4] * emit[0];
    float bad  = out_w[0] * baf[0] + out_w[1] * baf[1] + out_w[2] * baf[2] +
                 out_w[3] * baf[3] + out_w[4] * emit[1];
    float l1 = fmaxf(0.f, -(good - bad) + 1.f);
    out5[0] = l1; out5[1] = good; out5[2] = bad; out5[3] = l1; out5[4] = l1;
  }
}

extern "C" void kernel_launch(void* const* d_in, const int* in_sizes, int n_in,
                              void* d_out, int out_size, void* d_ws, size_t ws_size,
                              hipStream_t stream) {
  (void)in_sizes; (void)n_in; (void)out_size; (void)ws_size;
  const int* question   = (const int*)d_in[0];
  const int* doc1       = (const int*)d_in[1];
  const int* doc2       = (const int*)d_in[2];
  const float* doc1_sim = (const float*)d_in[3];
  const float* doc2_sim = (const float*)d_in[4];
  const float* gaf      = (const float*)d_in[5];
  const float* baf      = (const float*)d_in[6];
  const float* emb      = (const float*)d_in[7];
  const float* idf      = (const float*)d_in[8];
  const float* conv_w   = (const float*)d_in[9];
  const float* conv_b   = (const float*)d_in[10];
  const float* qw_w     = (const float*)d_in[11];
  const float* qw_b     = (const float*)d_in[12];
  const float* lin1_w   = (const float*)d_in[13];
  const float* lin2_w   = (const float*)d_in[14];
  const float* out_w    = (const float*)d_in[15];
  float* out = (float*)d_out;

  char* p = (char*)d_ws;
  ushort_t* qbe  = (ushort_t*)p; p += (size_t)(QQ + 2) * KP * 2;
  ushort_t* d1be = (ushort_t*)p; p += (size_t)(DD + 2) * KP * 2;
  ushort_t* d2be = (ushort_t*)p; p += (size_t)(DD + 2) * KP * 2;
  ushort_t* qbc  = (ushort_t*)p; p += (size_t)QQ * KP * 2;
  ushort_t* d1bc = (ushort_t*)p; p += (size_t)DD * KP * 2;
  ushort_t* d2bc = (ushort_t*)p; p += (size_t)DD * KP * 2;
  ushort_t* wt2  = (ushort_t*)p; p += (size_t)570 * 512 * 2;
  float* sims = (float*)p; p += (size_t)4 * QQ * DD * 4;
  float* ohT1 = (float*)p; p += (size_t)QQ * DD * 4;
  float* ohT2 = (float*)p; p += (size_t)QQ * DD * 4;
  float* nq2  = (float*)p; p += QQ * 4;
  float* nd12 = (float*)p; p += DD * 4;
  float* nd22 = (float*)p; p += DD * 4;
  // zeroed-each-call accumulator block (contiguous 8320 floats)
  float* nqc2  = (float*)p; p += QQ * 4;
  float* nd1c2 = (float*)p; p += DD * 4;
  float* nd2c2 = (float*)p; p += DD * 4;
  float* qwacc = (float*)p; p += QQ * 4;
  float* pool  = (float*)p; p += 6 * QQ * 2 * 4;

  prep<<<PREP_BLOCKS, 256, 0, stream>>>(
      emb, question, doc1, doc2, conv_w, doc1_sim, doc2_sim,
      qbe, d1be, d2be, qbc, d1bc, d2bc, wt2, ohT1, ohT2,
      nq2, nd12, nd22, nqc2);

  conv_mfma<<<516, 256, 0, stream>>>(
      wt2, conv_b, qw_w, qbe, d1be, d2be, qbc, d1bc, d2bc,
      nqc2, nd1c2, nd2c2, qwacc);

  sim_mfma<<<dim3(DD / 32, 4), 256, 0, stream>>>(
      qbe, d1be, d2be, qbc, d1bc, d2bc,
      nq2, nd12, nd22, nqc2, nd1c2, nd2c2, sims);

  kmax_pool<<<dim3(QQ, 6), 256, 0, stream>>>(ohT1, ohT2, sims, pool);

  final_kernel<<<1, 64, 0, stream>>>(qwacc, idf, question, qw_w, qw_b, pool,
                                     lin1_w, lin2_w, out_w, gaf, baf, out);
}